// Round 1
// baseline (524.866 us; speedup 1.0000x reference)
//
#include <hip/hip_runtime.h>
#include <math.h>

// out[i, b*O + o] = input[b,i] * exp(W[i,o]) + bias[i,o]
// B=2048, I=512, O=128. Output 512 MiB fp32 -> HBM-write-bound stream.

typedef float f4 __attribute__((ext_vector_type(4)));

constexpr int IN_FEATS  = 512;
constexpr int OUT_FEATS = 128;
constexpr int BATCH     = 2048;
constexpr int B_PER_BLOCK = 64;   // each block: one i, 64 b's -> 32 KiB contiguous output

__global__ __launch_bounds__(256) void linear_nosum_kernel(
    const float* __restrict__ in,   // [BATCH, IN_FEATS]
    const float* __restrict__ w,    // [IN_FEATS, OUT_FEATS]
    const float* __restrict__ bi,   // [IN_FEATS, OUT_FEATS]
    float* __restrict__ out)        // [IN_FEATS, BATCH*OUT_FEATS]
{
    __shared__ float s_ew[OUT_FEATS];
    __shared__ float s_b[OUT_FEATS];
    __shared__ float s_in[B_PER_BLOCK];

    const int i  = blockIdx.y;
    const int b0 = blockIdx.x * B_PER_BLOCK;
    const int t  = threadIdx.x;

    // Stage exp(W[i,:]) and bias[i,:] once per block (amortizes exp 2048x),
    // plus the 64 input scalars this block needs.
    if (t < OUT_FEATS) {
        s_ew[t] = expf(w[i * OUT_FEATS + t]);
    } else {
        const int t2 = t - OUT_FEATS;
        s_b[t2] = bi[i * OUT_FEATS + t2];
    }
    if (t < B_PER_BLOCK) {
        s_in[t] = in[(size_t)(b0 + t) * IN_FEATS + i];
    }
    __syncthreads();

    const int o4   = t & 31;   // which float4 along O (0..31)
    const int bsub = t >> 5;   // 0..7: b-offset within each iteration group

    // Loop-invariant per thread: its float4 of exp(W) and bias.
    const f4 w4 = reinterpret_cast<const f4*>(s_ew)[o4];
    const f4 bb = reinterpret_cast<const f4*>(s_b)[o4];

    f4* outp = reinterpret_cast<f4*>(
        out + (size_t)i * ((size_t)BATCH * OUT_FEATS) + (size_t)b0 * OUT_FEATS);

    #pragma unroll
    for (int it = 0; it < B_PER_BLOCK / 8; ++it) {
        const int bl = it * 8 + bsub;            // local b index 0..63
        const float v = s_in[bl];                // LDS broadcast (conflict-free)
        f4 r = v * w4 + bb;                      // 4 FMAs
        // Wave writes 64 x 16B = 1 KiB contiguous; output is write-once ->
        // nontemporal to keep it out of L2.
        __builtin_nontemporal_store(r, outp + bl * 32 + o4);
    }
}

extern "C" void kernel_launch(void* const* d_in, const int* in_sizes, int n_in,
                              void* d_out, int out_size, void* d_ws, size_t ws_size,
                              hipStream_t stream) {
    const float* in = (const float*)d_in[0];
    const float* w  = (const float*)d_in[1];
    const float* bi = (const float*)d_in[2];
    float* out      = (float*)d_out;

    dim3 grid(BATCH / B_PER_BLOCK, IN_FEATS);   // (32, 512) = 16384 blocks
    linear_nosum_kernel<<<grid, dim3(256), 0, stream>>>(in, w, bi, out);
}